// Round 12
// baseline (327.554 us; speedup 1.0000x reference)
//
#include <hip/hip_runtime.h>

// CenterLoss R17: delete the sort + LDS data staging entirely.
// R16 post-mortem: reg-staging 124->99.6us (686->856 GB/s) - global_load_lds
// was only part of the wall. Remaining per-iter chain: ds_write x2 ->
// lgkmcnt(0) -> 12 ds_read -> 3 ds_add, latency-exposed (VALUBusy 4%, occ
// 20.6%, conflicts benign). LDS throughput (~12us) + HBM floor (~21us) don't
// explain 99.6 -> it's the serialized chain. R17: lane holds its OWN 8 t's
// (coalesced float4 pair) + 8 labels in regs; 8 direct ds_add into
// S_lds[label][d]. No ds_write/ds_read/sort/prefix. Depth-3 reg prefetch,
// zero barriers, LDS ~18KB. GAP SOLVED: total-k_main = 148.8+-0.4us across
// R8/R9/R10/R16 = harness input re-poison (124.6MB ~ 838 GB/s). Fixed cost.
// Pre-commit: k_main >= 90us kills chain theory -> probe pure-load next.

#define NT 2048
#define NC 64
#define TQ 512          // t per block

// ws float offsets (identical to R9..R16 - proven)
#define OFF_S     0        // [8192] fallback atomic S (zeroed)
#define OFF_CNT   8192     // [64] int counts (global atomic, zeroed)
#define OFF_SSP   8256     // [1024] per-block sumsq
#define OFF_CROSS 9280     // [256]
#define OFF_CC    9536     // [256]
#define OFF_P     9792     // [1024][4096] per-block partials (main path)
#define WS_NEED_BYTES ((size_t)(OFF_P + 1024 * 4096) * 4)

template <bool PARTIAL>
__global__ __launch_bounds__(256) void k_main(const float* __restrict__ feat,
                                              const int*  __restrict__ label,
                                              float* __restrict__ ws) {
    __shared__ float S_lds[NC][65];   // 16.6 KB; stride 65 -> bank = (c+d)%32
    __shared__ float red[256];
    __shared__ int cnt[NC];
    // ~17.9 KB/block -> LDS allows 8 blocks/CU; grid gives 4 (16 waves/CU)

    const int tid = threadIdx.x, bid = blockIdx.x;
    const int b = bid >> 3, dh = (bid >> 2) & 1, th = bid & 3;
    const int w = tid >> 6, lane = tid & 63;

    // ---- init ----
    for (int j = tid; j < NC * 65; j += 256) ((float*)S_lds)[j] = 0.0f;
    if (tid < NC) cnt[tid] = 0;
    __syncthreads();

    // ---- histogram of this block's 512 labels (for counts only) ----
    const int* lbase = label + b * NT + th * TQ;
    {
        const int2 L = *(const int2*)(lbase + tid * 2);
        atomicAdd(&cnt[L.x], 1); atomicAdd(&cnt[L.y], 1);
    }

    // ---- lane's 8 labels -> S_lds row byte offsets (loaded once) ----
    const int4 LA = *(const int4*)(lbase + 4 * lane);         // t = 4l..4l+3
    const int4 LB = *(const int4*)(lbase + 256 + 4 * lane);   // t = 256+4l..
    char* const Sb = (char*)&S_lds[0][0];
    const int o0 = LA.x * 260, o1 = LA.y * 260, o2 = LA.z * 260, o3 = LA.w * 260;
    const int o4 = LB.x * 260, o5 = LB.y * 260, o6 = LB.z * 260, o7 = LB.w * 260;

    // ---- hot loop: wave w owns rows w+4i; depth-3 rolling reg prefetch ----
    // Lane loads ITS OWN float4 pair of each row (fully coalesced 1KB/wave
    // per load) and atomically adds each element into S_lds[label][d].
    // No LDS writes/reads of data, no barriers, no counted waitcnts -
    // compiler inserts exact vmcnt before first use of each float4.
    const float* fbase = feat + ((size_t)b * 128 + dh * 64) * NT + th * TQ;
    float ssA = 0.0f, ssB = 0.0f;

    float4 A0, B0, A1, B1, A2, B2;
    {
        const float* r0 = fbase + (size_t)(w     ) * NT;
        const float* r1 = fbase + (size_t)(w +  4) * NT;
        const float* r2 = fbase + (size_t)(w +  8) * NT;
        A0 = *(const float4*)(r0 + 4 * lane); B0 = *(const float4*)(r0 + 256 + 4 * lane);
        A1 = *(const float4*)(r1 + 4 * lane); B1 = *(const float4*)(r1 + 256 + 4 * lane);
        A2 = *(const float4*)(r2 + 4 * lane); B2 = *(const float4*)(r2 + 256 + 4 * lane);
    }

    #pragma unroll
    for (int i = 0; i < 16; ++i) {
        float4 a, bb;
        const int sl = i % 3;                 // compile-time after full unroll
        if (sl == 0) {
            a = A0; bb = B0;
            if (i + 3 < 16) {
                const float* rp = fbase + (size_t)(w + 4 * (i + 3)) * NT;
                A0 = *(const float4*)(rp + 4 * lane);
                B0 = *(const float4*)(rp + 256 + 4 * lane);
            }
        } else if (sl == 1) {
            a = A1; bb = B1;
            if (i + 3 < 16) {
                const float* rp = fbase + (size_t)(w + 4 * (i + 3)) * NT;
                A1 = *(const float4*)(rp + 4 * lane);
                B1 = *(const float4*)(rp + 256 + 4 * lane);
            }
        } else {
            a = A2; bb = B2;
            if (i + 3 < 16) {
                const float* rp = fbase + (size_t)(w + 4 * (i + 3)) * NT;
                A2 = *(const float4*)(rp + 4 * lane);
                B2 = *(const float4*)(rp + 256 + 4 * lane);
            }
        }

        const int db = (w + 4 * i) << 2;      // byte offset of d-column (<=252)
        atomicAdd((float*)(Sb + o0 + db), a.x);
        atomicAdd((float*)(Sb + o1 + db), a.y);
        atomicAdd((float*)(Sb + o2 + db), a.z);
        atomicAdd((float*)(Sb + o3 + db), a.w);
        atomicAdd((float*)(Sb + o4 + db), bb.x);
        atomicAdd((float*)(Sb + o5 + db), bb.y);
        atomicAdd((float*)(Sb + o6 + db), bb.z);
        atomicAdd((float*)(Sb + o7 + db), bb.w);
        ssA += a.x * a.x + a.y * a.y + a.z * a.z + a.w * a.w;
        ssB += bb.x * bb.x + bb.y * bb.y + bb.z * bb.z + bb.w * bb.w;
    }

    // ---- global counts (one label-slice per (b,th); gate on dh==0) ----
    if (dh == 0 && tid < NC) atomicAdd((int*)(ws + OFF_CNT) + tid, cnt[tid]);

    __syncthreads();         // all waves' ds_add_f32 drained; S_lds complete
    if (PARTIAL) {
        // non-atomic flush: block-contiguous 4096 floats, fully coalesced
        const int c = tid >> 2, j0 = (tid & 3) * 16;
        float* gP = ws + OFF_P + (size_t)bid * 4096 + c * 64 + j0;
        float4 v0, v1, v2, v3;
        v0.x = S_lds[c][j0 +  0]; v0.y = S_lds[c][j0 +  1];
        v0.z = S_lds[c][j0 +  2]; v0.w = S_lds[c][j0 +  3];
        v1.x = S_lds[c][j0 +  4]; v1.y = S_lds[c][j0 +  5];
        v1.z = S_lds[c][j0 +  6]; v1.w = S_lds[c][j0 +  7];
        v2.x = S_lds[c][j0 +  8]; v2.y = S_lds[c][j0 +  9];
        v2.z = S_lds[c][j0 + 10]; v2.w = S_lds[c][j0 + 11];
        v3.x = S_lds[c][j0 + 12]; v3.y = S_lds[c][j0 + 13];
        v3.z = S_lds[c][j0 + 14]; v3.w = S_lds[c][j0 + 15];
        *(float4*)gP        = v0;
        *(float4*)(gP + 4)  = v1;
        *(float4*)(gP + 8)  = v2;
        *(float4*)(gP + 12) = v3;
    } else {
        // fallback: global atomic flush (R8 path; correct, slow)
        const int c = tid >> 2, j0 = (tid & 3) * 16;
        float* gS = ws + OFF_S + (size_t)c * 128 + dh * 64 + j0;
        #pragma unroll
        for (int j = 0; j < 16; ++j) atomicAdd(&gS[j], S_lds[c][j0 + j]);
    }

    // ---- block sumsq reduce ----
    red[tid] = ssA + ssB;
    __syncthreads();
    for (int s = 128; s > 0; s >>= 1) {
        if (tid < s) red[tid] += red[tid + s];
        __syncthreads();
    }
    if (tid == 0) ws[OFF_SSP + bid] = red[0];
}

// main-path reduction: each block owns 32 (c,d) elements; 8 slices sum 64
// partial-blocks each (512 contributors per element = 128 b x 4 th).
__global__ __launch_bounds__(256) void k_red_p(float* __restrict__ ws,
                                               const float* __restrict__ centers,
                                               float* __restrict__ out) {
    const int tid = threadIdx.x, bid = blockIdx.x;
    const int j = tid & 31, s = tid >> 5;
    const int e = bid * 32 + j;
    const int c = e >> 7, d = e & 127, dhh = d >> 6, dl = d & 63;

    const float* base = ws + OFF_P + ((size_t)dhh * 4) * 4096 + c * 64 + dl;
    float sum = 0.0f;
    for (int b = s * 16; b < s * 16 + 16; ++b) {
        const float* pb = base + (size_t)b * 8 * 4096;
        sum += (pb[0] + pb[4096]) + (pb[2 * 4096] + pb[3 * 4096]);
    }

    __shared__ float red[256];
    red[tid] = sum;
    __syncthreads();
    if (tid < 128) red[tid] += red[tid + 128];
    __syncthreads();
    if (tid < 64)  red[tid] += red[tid + 64];
    __syncthreads();

    if (tid < 32) {
        const float tot = red[tid] + red[tid + 32];
        const float cn  = (float)((const int*)(ws + OFF_CNT))[c];
        const float ctr = centers[e];
        const float den = cn > 1.0f ? cn : 1.0f;
        out[1 + e] = (cn * ctr - tot) / den;

        float r1 = tot * ctr;          // cross term
        float r2 = cn * ctr * ctr;     // center-norm term
        for (int o = 16; o > 0; o >>= 1) {
            r1 += __shfl_down(r1, o, 32);
            r2 += __shfl_down(r2, o, 32);
        }
        if (tid == 0) { ws[OFF_CROSS + bid] = r1; ws[OFF_CC + bid] = r2; }
    }
}

// fallback reduction over the atomic S (R8 path)
__global__ __launch_bounds__(256) void k_red_a(float* __restrict__ ws,
                                               const float* __restrict__ centers,
                                               float* __restrict__ out) {
    const int tid = threadIdx.x, bid = blockIdx.x;
    const int e = bid * 256 + tid, c = e >> 7;
    const float sum = ws[OFF_S + e];
    const float cn  = (float)((const int*)(ws + OFF_CNT))[c];
    const float ctr = centers[e];
    const float den = cn > 1.0f ? cn : 1.0f;
    out[1 + e] = (cn * ctr - sum) / den;

    __shared__ float r1[256], r2[256];
    r1[tid] = sum * ctr;
    r2[tid] = cn * ctr * ctr;
    __syncthreads();
    for (int k = 128; k > 0; k >>= 1) {
        if (tid < k) { r1[tid] += r1[tid + k]; r2[tid] += r2[tid + k]; }
        __syncthreads();
    }
    if (tid == 0) { ws[OFF_CROSS + bid] = r1[0]; ws[OFF_CC + bid] = r2[0]; }
}

__global__ __launch_bounds__(256) void k_epi(const float* __restrict__ ws,
                                             float* __restrict__ out,
                                             int ncross) {
    const int tid = threadIdx.x;
    __shared__ float r[256];
    float s = ws[OFF_SSP + tid] + ws[OFF_SSP + tid + 256]
            + ws[OFF_SSP + tid + 512] + ws[OFF_SSP + tid + 768];
    if (tid < ncross) s += ws[OFF_CC + tid] - 2.0f * ws[OFF_CROSS + tid];
    r[tid] = s;
    __syncthreads();
    for (int k = 128; k > 0; k >>= 1) {
        if (tid < k) r[tid] += r[tid + k];
        __syncthreads();
    }
    if (tid == 0) out[0] = r[0] * (1.0f / 33554432.0f);  // / (N*D), N = B*T
}

extern "C" void kernel_launch(void* const* d_in, const int* in_sizes, int n_in,
                              void* d_out, int out_size, void* d_ws, size_t ws_size,
                              hipStream_t stream) {
    const float* feat    = (const float*)d_in[0];
    const int*   label   = (const int*)d_in[1];
    const float* centers = (const float*)d_in[2];
    float* out = (float*)d_out;
    float* ws  = (float*)d_ws;

    // zero atomic accumulators (S fallback + CNT); capture-safe stream op
    hipMemsetAsync(ws, 0, 8256 * sizeof(float), stream);

    if (ws_size >= WS_NEED_BYTES) {
        hipLaunchKernelGGL(k_main<true>,  dim3(1024), dim3(256), 0, stream, feat, label, ws);
        hipLaunchKernelGGL(k_red_p, dim3(256), dim3(256), 0, stream, ws, centers, out);
        hipLaunchKernelGGL(k_epi,   dim3(1),   dim3(256), 0, stream, ws, out, 256);
    } else {
        hipLaunchKernelGGL(k_main<false>, dim3(1024), dim3(256), 0, stream, feat, label, ws);
        hipLaunchKernelGGL(k_red_a, dim3(32),  dim3(256), 0, stream, ws, centers, out);
        hipLaunchKernelGGL(k_epi,   dim3(1),   dim3(256), 0, stream, ws, out, 32);
    }
}

// Round 15
// 212.845 us; speedup vs baseline: 1.5389x; 1.5389x over previous
//
#include <hip/hip_runtime.h>

// CenterLoss R20 == R18/R19 resubmitted verbatim (7th broker timeout; the
// zero-atomic structure has never executed). Holding for attribution.
// Sixth audit adds rule-#20 check: all hot-loop array indices are static
// after unroll (acc[i], off[j], parity-split regs) -> no scratch spill.
// cl==0 lanes store 0.0 rows == segment_sum zero rows; diff -> cn*ctr/den. OK.
//
// Atomic-wall model (3 measured points): dur ~ 3.75us/M-ds_add + 52us
// (R16 12.6M->99.6us, R17 33.5M->178us == R1-R3's 180 invariant). This
// kernel: lane l of wave w owns class l x d-range [16w,16w+16); wave stages
// rows privately (2-slot dbuf, depth-2 reg prefetch); lane gathers its
// class's cnt values (24 static predicated offsets + rare dynamic tail)
// into REGISTER acc[16]; single-owner plain stores to S_lds. ZERO atomics/
// barriers/manual-waitcnt in the hot loop. Re-poison gap (148.8us) is fixed
// harness cost; target is k_main alone.
// Pre-commit: k_main >= 90us kills atomic model -> pure-load probe next.

#define NT 2048
#define NC 64
#define TQ 512          // t per block
#define RB 520          // row slot floats (16B multiple)
#define UNR 24          // static gather offsets per lane (P(cnt>24)~1e-9/inst)

// ws float offsets (identical to R9..R17 - proven)
#define OFF_S     0        // [8192] fallback atomic S (zeroed)
#define OFF_CNT   8192     // [64] int counts (global atomic, zeroed)
#define OFF_SSP   8256     // [1024] per-block sumsq
#define OFF_CROSS 9280     // [256]
#define OFF_CC    9536     // [256]
#define OFF_P     9792     // [1024][4096] per-block partials (main path)
#define WS_NEED_BYTES ((size_t)(OFF_P + 1024 * 4096) * 4)

template <bool PARTIAL>
__global__ __launch_bounds__(256) void k_main(const float* __restrict__ feat,
                                              const int*  __restrict__ label,
                                              float* __restrict__ ws) {
    __shared__ float __attribute__((aligned(16))) rowbuf[4][2][RB]; // 16.6 KB wave-private dbuf
    __shared__ unsigned short __attribute__((aligned(16))) sorted[512];
    __shared__ float S_lds[NC][65];                                  // 16.6 KB, single-owner cells
    __shared__ float red[256];
    __shared__ int cnt[NC], pstart[NC], cursor[NC];
    // ~35.9 KB/block -> 4 blocks/CU

    const int tid = threadIdx.x, bid = blockIdx.x;
    const int b = bid >> 3, dh = (bid >> 2) & 1, th = bid & 3;
    const int w = tid >> 6, lane = tid & 63;

    if (tid < NC) { cnt[tid] = 0; cursor[tid] = 0; }
    __syncthreads();

    // ---- histogram of this block's 512 labels ----
    const int* lbase = label + b * NT + th * TQ;
    const int2 L = *(const int2*)(lbase + tid * 2);
    atomicAdd(&cnt[L.x], 1); atomicAdd(&cnt[L.y], 1);
    __syncthreads();

    // ---- exact prefix (no padding needed: ownership, not grouping) ----
    if (tid == 0) {
        int pt = 0;
        for (int c = 0; c < NC; ++c) { pstart[c] = pt; pt += cnt[c]; }
    }
    __syncthreads();

    // ---- scatter: sorted[pos] = byte offset of t within a row ----
    {
        int p = pstart[L.x] + atomicAdd(&cursor[L.x], 1);
        sorted[p] = (unsigned short)((tid * 2 + 0) * 4);
        p = pstart[L.y] + atomicAdd(&cursor[L.y], 1);
        sorted[p] = (unsigned short)((tid * 2 + 1) * 4);
    }
    __syncthreads();

    // ---- lane owns class=lane: preload up to UNR offsets (static regs) ----
    const int cl = cnt[lane], ps = pstart[lane];
    int off[UNR];
    #pragma unroll
    for (int j = 0; j < UNR; ++j) off[j] = (j < cl) ? (int)sorted[ps + j] : 0;

    // wave max count (uniform) for quad early-exit
    int wm = cl;
    #pragma unroll
    for (int o = 32; o >= 1; o >>= 1) { int t = __shfl_xor(wm, o); wm = wm > t ? wm : t; }

    // ---- hot loop: wave w owns rows 16w..16w+15; zero atomics/barriers ----
    const float* fbase = feat + ((size_t)b * 128 + dh * 64) * NT + th * TQ;
    float acc[16];
    #pragma unroll
    for (int j = 0; j < 16; ++j) acc[j] = 0.0f;
    float ss = 0.0f;

    float4 Ae, Be, Ao, Bo;                    // pair[parity] of staged rows
    {
        const float* r0 = fbase + (size_t)(16 * w) * NT;
        const float* r1 = fbase + (size_t)(16 * w + 1) * NT;
        Ae = *(const float4*)(r0 + 4 * lane); Be = *(const float4*)(r0 + 256 + 4 * lane);
        Ao = *(const float4*)(r1 + 4 * lane); Bo = *(const float4*)(r1 + 256 + 4 * lane);
    }
    {   // prologue: write row 0 -> slot 0
        float* d0 = &rowbuf[w][0][0];
        *(float4*)(d0 + 4 * lane) = Ae; *(float4*)(d0 + 256 + 4 * lane) = Be;
    }

    #pragma unroll
    for (int i = 0; i < 16; ++i) {
        // gather row i from slot i&1 (written in iter i-1; same-wave LDS is
        // in-order and the compiler's alias analysis orders write->read)
        const char* rb = (const char*)&rowbuf[w][i & 1][0];
        #pragma unroll
        for (int qb = 0; qb < UNR / 4; ++qb) {
            if (qb * 4 < wm) {                 // wave-uniform early exit
                #pragma unroll
                for (int k = 0; k < 4; ++k) {
                    const int j = qb * 4 + k;
                    if (j < cl) {
                        const float v = *(const float*)(rb + off[j]);
                        acc[i] += v; ss += v * v;
                    }
                }
            }
        }
        if (cl > UNR) {                        // ultra-rare dynamic tail
            for (int j = UNR; j < cl; ++j) {
                const float v = *(const float*)(rb + (int)sorted[ps + j]);
                acc[i] += v; ss += v * v;
            }
        }
        if (i < 15) {                          // write row i+1 -> slot (i+1)&1
            float* dst = &rowbuf[w][(i + 1) & 1][0];
            if ((i + 1) & 1) { *(float4*)(dst + 4 * lane) = Ao; *(float4*)(dst + 256 + 4 * lane) = Bo; }
            else             { *(float4*)(dst + 4 * lane) = Ae; *(float4*)(dst + 256 + 4 * lane) = Be; }
            if (i + 2 < 16) {                  // load row i+2 -> pair[i&1]
                const float* rp = fbase + (size_t)(16 * w + i + 2) * NT;
                if (i & 1) { Ao = *(const float4*)(rp + 4 * lane); Bo = *(const float4*)(rp + 256 + 4 * lane); }
                else       { Ae = *(const float4*)(rp + 4 * lane); Be = *(const float4*)(rp + 256 + 4 * lane); }
            }
        }
    }

    // ---- single-owner result stores (no atomics; 2-way banked) ----
    #pragma unroll
    for (int j = 0; j < 16; ++j) S_lds[lane][16 * w + j] = acc[j];

    // ---- global counts (one label-slice per (b,th); gate on dh==0) ----
    if (dh == 0 && tid < NC) atomicAdd((int*)(ws + OFF_CNT) + tid, cnt[tid]);

    __syncthreads();         // S_lds complete across waves
    if (PARTIAL) {
        // non-atomic flush: block-contiguous 4096 floats, fully coalesced
        const int c = tid >> 2, j0 = (tid & 3) * 16;
        float* gP = ws + OFF_P + (size_t)bid * 4096 + c * 64 + j0;
        float4 v0, v1, v2, v3;
        v0.x = S_lds[c][j0 +  0]; v0.y = S_lds[c][j0 +  1];
        v0.z = S_lds[c][j0 +  2]; v0.w = S_lds[c][j0 +  3];
        v1.x = S_lds[c][j0 +  4]; v1.y = S_lds[c][j0 +  5];
        v1.z = S_lds[c][j0 +  6]; v1.w = S_lds[c][j0 +  7];
        v2.x = S_lds[c][j0 +  8]; v2.y = S_lds[c][j0 +  9];
        v2.z = S_lds[c][j0 + 10]; v2.w = S_lds[c][j0 + 11];
        v3.x = S_lds[c][j0 + 12]; v3.y = S_lds[c][j0 + 13];
        v3.z = S_lds[c][j0 + 14]; v3.w = S_lds[c][j0 + 15];
        *(float4*)gP        = v0;
        *(float4*)(gP + 4)  = v1;
        *(float4*)(gP + 8)  = v2;
        *(float4*)(gP + 12) = v3;
    } else {
        // fallback: global atomic flush (correct, slow)
        const int c = tid >> 2, j0 = (tid & 3) * 16;
        float* gS = ws + OFF_S + (size_t)c * 128 + dh * 64 + j0;
        #pragma unroll
        for (int j = 0; j < 16; ++j) atomicAdd(&gS[j], S_lds[c][j0 + j]);
    }

    // ---- block sumsq reduce ----
    red[tid] = ss;
    __syncthreads();
    for (int s = 128; s > 0; s >>= 1) {
        if (tid < s) red[tid] += red[tid + s];
        __syncthreads();
    }
    if (tid == 0) ws[OFF_SSP + bid] = red[0];
}

// main-path reduction: each block owns 32 (c,d) elements; 8 slices sum 64
// partial-blocks each (512 contributors per element = 128 b x 4 th).
__global__ __launch_bounds__(256) void k_red_p(float* __restrict__ ws,
                                               const float* __restrict__ centers,
                                               float* __restrict__ out) {
    const int tid = threadIdx.x, bid = blockIdx.x;
    const int j = tid & 31, s = tid >> 5;
    const int e = bid * 32 + j;
    const int c = e >> 7, d = e & 127, dhh = d >> 6, dl = d & 63;

    const float* base = ws + OFF_P + ((size_t)dhh * 4) * 4096 + c * 64 + dl;
    float sum = 0.0f;
    for (int b = s * 16; b < s * 16 + 16; ++b) {
        const float* pb = base + (size_t)b * 8 * 4096;
        sum += (pb[0] + pb[4096]) + (pb[2 * 4096] + pb[3 * 4096]);
    }

    __shared__ float red[256];
    red[tid] = sum;
    __syncthreads();
    if (tid < 128) red[tid] += red[tid + 128];
    __syncthreads();
    if (tid < 64)  red[tid] += red[tid + 64];
    __syncthreads();

    if (tid < 32) {
        const float tot = red[tid] + red[tid + 32];
        const float cn  = (float)((const int*)(ws + OFF_CNT))[c];
        const float ctr = centers[e];
        const float den = cn > 1.0f ? cn : 1.0f;
        out[1 + e] = (cn * ctr - tot) / den;

        float r1 = tot * ctr;          // cross term
        float r2 = cn * ctr * ctr;     // center-norm term
        for (int o = 16; o > 0; o >>= 1) {
            r1 += __shfl_down(r1, o, 32);
            r2 += __shfl_down(r2, o, 32);
        }
        if (tid == 0) { ws[OFF_CROSS + bid] = r1; ws[OFF_CC + bid] = r2; }
    }
}

// fallback reduction over the atomic S
__global__ __launch_bounds__(256) void k_red_a(float* __restrict__ ws,
                                               const float* __restrict__ centers,
                                               float* __restrict__ out) {
    const int tid = threadIdx.x, bid = blockIdx.x;
    const int e = bid * 256 + tid, c = e >> 7;
    const float sum = ws[OFF_S + e];
    const float cn  = (float)((const int*)(ws + OFF_CNT))[c];
    const float ctr = centers[e];
    const float den = cn > 1.0f ? cn : 1.0f;
    out[1 + e] = (cn * ctr - sum) / den;

    __shared__ float r1[256], r2[256];
    r1[tid] = sum * ctr;
    r2[tid] = cn * ctr * ctr;
    __syncthreads();
    for (int k = 128; k > 0; k >>= 1) {
        if (tid < k) { r1[tid] += r1[tid + k]; r2[tid] += r2[tid + k]; }
        __syncthreads();
    }
    if (tid == 0) { ws[OFF_CROSS + bid] = r1[0]; ws[OFF_CC + bid] = r2[0]; }
}

__global__ __launch_bounds__(256) void k_epi(const float* __restrict__ ws,
                                             float* __restrict__ out,
                                             int ncross) {
    const int tid = threadIdx.x;
    __shared__ float r[256];
    float s = ws[OFF_SSP + tid] + ws[OFF_SSP + tid + 256]
            + ws[OFF_SSP + tid + 512] + ws[OFF_SSP + tid + 768];
    if (tid < ncross) s += ws[OFF_CC + tid] - 2.0f * ws[OFF_CROSS + tid];
    r[tid] = s;
    __syncthreads();
    for (int k = 128; k > 0; k >>= 1) {
        if (tid < k) r[tid] += r[tid + k];
        __syncthreads();
    }
    if (tid == 0) out[0] = r[0] * (1.0f / 33554432.0f);  // / (N*D), N = B*T
}

extern "C" void kernel_launch(void* const* d_in, const int* in_sizes, int n_in,
                              void* d_out, int out_size, void* d_ws, size_t ws_size,
                              hipStream_t stream) {
    const float* feat    = (const float*)d_in[0];
    const int*   label   = (const int*)d_in[1];
    const float* centers = (const float*)d_in[2];
    float* out = (float*)d_out;
    float* ws  = (float*)d_ws;

    // zero atomic accumulators (S fallback + CNT); capture-safe stream op
    hipMemsetAsync(ws, 0, 8256 * sizeof(float), stream);

    if (ws_size >= WS_NEED_BYTES) {
        hipLaunchKernelGGL(k_main<true>,  dim3(1024), dim3(256), 0, stream, feat, label, ws);
        hipLaunchKernelGGL(k_red_p, dim3(256), dim3(256), 0, stream, ws, centers, out);
        hipLaunchKernelGGL(k_epi,   dim3(1),   dim3(256), 0, stream, ws, out, 256);
    } else {
        hipLaunchKernelGGL(k_main<false>, dim3(1024), dim3(256), 0, stream, feat, label, ws);
        hipLaunchKernelGGL(k_red_a, dim3(32),  dim3(256), 0, stream, ws, centers, out);
        hipLaunchKernelGGL(k_epi,   dim3(1),   dim3(256), 0, stream, ws, out, 32);
    }
}